// Round 13
// baseline (95.319 us; speedup 1.0000x reference)
//
#include <hip/hip_runtime.h>
#include <hip/hip_bf16.h>
#include <math.h>
#include <float.h>

// Problem constants
#define BSZ 16
#define SEQ 4096
#define HID 768
#define H4  192      // HID/4
#define NM  128
#define NSPAN 256
#define ENT 256
#define NTOT 2048
#define SC  64
#define NCH 64

typedef __attribute__((ext_vector_type(8))) short bfx8;
typedef __attribute__((ext_vector_type(4))) float f32x4;

static __device__ __forceinline__ unsigned short f2bf(float x) {
  unsigned int u = __float_as_uint(x);
  unsigned int r = (u + 0x7fff + ((u >> 16) & 1)) >> 16;  // RNE
  return (unsigned short)r;
}

static __device__ __forceinline__ bfx8 pack8(float4 v0, float4 v1) {
  bfx8 p;
  p[0] = (short)f2bf(v0.x); p[1] = (short)f2bf(v0.y);
  p[2] = (short)f2bf(v0.z); p[3] = (short)f2bf(v0.w);
  p[4] = (short)f2bf(v1.x); p[5] = (short)f2bf(v1.y);
  p[6] = (short)f2bf(v1.z); p[7] = (short)f2bf(v1.w);
  return p;
}

// ---------------------------------------------------------------------------
// K1: scan + prep fused as independent block roles. NO device fences.
//  blocks 0..1023   : chunked scan (b=bid>>6, c=bid&63) -> W, P(chunk sums)
//  blocks 1024..1151: prep — vectorized LWb convert + LEb label-emb gather
// ---------------------------------------------------------------------------
__global__ __launch_bounds__(192) void k1_scan_prep_kernel(
    const float* __restrict__ seq, const int* __restrict__ spans,
    float* __restrict__ W, float* __restrict__ P,
    const float* __restrict__ lw, unsigned short* __restrict__ LWb,
    const float* __restrict__ table, const int* __restrict__ labels,
    unsigned short* __restrict__ LEb) {
  int bid = blockIdx.x, t = threadIdx.x;

  if (bid >= BSZ * NCH) {
    // ---- prep role (8-wide vectorized, G13) ----
    int tid = (bid - BSZ * NCH) * 192 + t;  // 0..24575
    {  // LWb: 196608 elems = 24576 chunks of 8 — exactly one per thread
      const float4* s = reinterpret_cast<const float4*>(lw) + (size_t)tid * 2;
      float4 v0 = s[0], v1 = s[1];
      *reinterpret_cast<bfx8*>(LWb + (size_t)tid * 8) = pack8(v0, v1);
    }
    for (int i8 = tid; i8 < NTOT * 32; i8 += 24576) {  // LEb: 65536 chunks
      int j = i8 >> 5, e8 = i8 & 31;
      int lab = labels[(j >> 7) * 256 + (j & 127)];  // labels[b][0][m]
      const float4* s =
          reinterpret_cast<const float4*>(table + (size_t)lab * ENT) + e8 * 2;
      float4 v0 = s[0], v1 = s[1];
      *reinterpret_cast<bfx8*>(LEb + (size_t)j * ENT + e8 * 8) = pack8(v0, v1);
    }
    return;
  }

  // ---- span-scan role ----
  int b = bid >> 6;
  int c = bid & 63;

  __shared__ int head[SC + 1];
  __shared__ int nxt[NSPAN];
  __shared__ unsigned int maskw[2];
  __shared__ int has_end;
  for (int i = t; i < SC + 1; i += 192) head[i] = -1;
  if (t < 2) maskw[t] = 0u;
  if (t == 0) has_end = 0;
  __syncthreads();
  for (int j = t; j < NSPAN; j += 192) {
    int e = spans[b * NSPAN + j];
    int ch = e >> 6; if (ch > NCH - 1) ch = NCH - 1;
    if (ch == c) {
      int off = e - c * SC;
      nxt[j] = atomicExch(&head[off], j);
      if (off < SC) atomicOr(&maskw[off >> 5], 1u << (off & 31));
      else has_end = 1;
    }
  }
  __syncthreads();
  unsigned long long mask = ((unsigned long long)maskw[1] << 32) | maskw[0];
  int emit_end = has_end;

  const float4* seq4 =
      reinterpret_cast<const float4*>(seq) + (size_t)(b * SEQ + c * SC) * H4 + t;
  float4* W4 = reinterpret_cast<float4*>(W);
  float4 acc = make_float4(0.f, 0.f, 0.f, 0.f);
#pragma unroll 8
  for (int s = 0; s < SC; ++s) {
    if (mask & (1ull << s)) {
      for (int p = head[s]; p != -1; p = nxt[p]) {
        W4[(size_t)(b * NSPAN + p) * H4 + t] = acc;
      }
    }
    float4 v = seq4[(size_t)s * H4];
    acc.x += v.x; acc.y += v.y; acc.z += v.z; acc.w += v.w;
  }
  if (emit_end) {
    for (int p = head[SC]; p != -1; p = nxt[p]) {
      W4[(size_t)(b * NSPAN + p) * H4 + t] = acc;
    }
  }
  reinterpret_cast<float4*>(P)[(size_t)(b * NCH + c) * H4 + t] = acc;
}

// ---------------------------------------------------------------------------
// K2: exclusive prefix over chunk sums (batched loads, 16 blocks).
// ---------------------------------------------------------------------------
__global__ __launch_bounds__(192) void chunk_prefix_kernel(float* __restrict__ P) {
  int b = blockIdx.x;
  int h = threadIdx.x;
  float4* P4 = reinterpret_cast<float4*>(P) + (size_t)b * NCH * H4 + h;
  float4 run = make_float4(0.f, 0.f, 0.f, 0.f);
  for (int cb = 0; cb < NCH; cb += 16) {
    float4 v[16];
#pragma unroll
    for (int i = 0; i < 16; ++i) v[i] = P4[(size_t)(cb + i) * H4];
#pragma unroll
    for (int i = 0; i < 16; ++i) {
      P4[(size_t)(cb + i) * H4] = run;
      run.x += v[i].x; run.y += v[i].y; run.z += v[i].z; run.w += v[i].w;
    }
  }
}

// ---------------------------------------------------------------------------
// K3 (fused): MV staging -> EV MFMA -> logits MFMA -> softmax partials.
// Grid 256 x 256: rtile=bid>>2 (32 rows), ctile=bid&3 (512 logit cols).
// EV computed in-block (4x redundant across ctiles — MFMA-cheap, kills the
// EVb global round-trip and one launch); ctile==0 writes f32 EV to out.
// ---------------------------------------------------------------------------
#define APAD 776
__global__ __launch_bounds__(256) void fused_ev_loss_kernel(
    const float* __restrict__ W, const float* __restrict__ P,
    const int* __restrict__ spans, const unsigned short* __restrict__ LWb,
    const float* __restrict__ bias, const unsigned short* __restrict__ LEb,
    float* __restrict__ Pmax, float* __restrict__ Psum,
    float* __restrict__ Pdiag, float* __restrict__ out) {
  int t = threadIdx.x;
  int bid = blockIdx.x;
  int ctile = bid & 3, rtile = bid >> 2;
  int i0 = rtile * 32, c0 = ctile * 512;

  __shared__ unsigned short Ab[32][APAD];
  __shared__ unsigned short A2[32][264];
  __shared__ float redm[4][32], reds[4][32];

  // ---- phase 1: stage 32 mention-vector rows (f32 math -> bf16 LDS) ----
  const float4* W4 = reinterpret_cast<const float4*>(W);
  const float4* P4 = reinterpret_cast<const float4*>(P);
  for (int it = 0; it < 24; ++it) {
    int q = it * 256 + t;            // 0..6143
    int r = q / H4, h = q - r * H4;
    int bm = i0 + r;
    int b = bm >> 7, m = bm & (NM - 1);
    int e0 = spans[bm * 2], e1 = spans[bm * 2 + 1];
    int cc0 = e0 >> 6; if (cc0 > NCH - 1) cc0 = NCH - 1;
    int cc1 = e1 >> 6; if (cc1 > NCH - 1) cc1 = NCH - 1;
    float4 p0 = P4[(size_t)(b * NCH + cc0) * H4 + h];
    float4 p1 = P4[(size_t)(b * NCH + cc1) * H4 + h];
    float4 w0 = W4[(size_t)(b * NSPAN + 2 * m) * H4 + h];
    float4 w1 = W4[(size_t)(b * NSPAN + 2 * m + 1) * H4 + h];
    int len = e1 - e0;
    float inv = len > 0 ? 1.f / (float)len : 0.f;  // len==0 -> 0 (nan_to_num)
    ushort4 pk;
    pk.x = f2bf(((p1.x + w1.x) - (p0.x + w0.x)) * inv);
    pk.y = f2bf(((p1.y + w1.y) - (p0.y + w0.y)) * inv);
    pk.z = f2bf(((p1.z + w1.z) - (p0.z + w0.z)) * inv);
    pk.w = f2bf(((p1.w + w1.w) - (p0.w + w0.w)) * inv);
    *reinterpret_cast<ushort4*>(&Ab[r][h * 4]) = pk;
  }
  __syncthreads();

  int w = t >> 6, l = t & 63;
  int lr = l & 15, lg = l >> 4;

  // ---- phase 2: EV rows via MFMA; wave w covers cols w*64..w*64+63 ----
  {
    f32x4 eacc[2][4];
#pragma unroll
    for (int mt = 0; mt < 2; ++mt)
#pragma unroll
      for (int nt = 0; nt < 4; ++nt) eacc[mt][nt] = (f32x4)(0.f);
    for (int ks = 0; ks < 24; ++ks) {
      bfx8 a0 = *reinterpret_cast<const bfx8*>(&Ab[lr][ks * 32 + lg * 8]);
      bfx8 a1 = *reinterpret_cast<const bfx8*>(&Ab[16 + lr][ks * 32 + lg * 8]);
#pragma unroll
      for (int nt = 0; nt < 4; ++nt) {
        int col = w * 64 + nt * 16 + lr;
        bfx8 bf = *reinterpret_cast<const bfx8*>(
            &LWb[(size_t)col * HID + ks * 32 + lg * 8]);
        eacc[0][nt] = __builtin_amdgcn_mfma_f32_16x16x32_bf16(a0, bf, eacc[0][nt], 0, 0, 0);
        eacc[1][nt] = __builtin_amdgcn_mfma_f32_16x16x32_bf16(a1, bf, eacc[1][nt], 0, 0, 0);
      }
    }
#pragma unroll
    for (int mt = 0; mt < 2; ++mt) {
#pragma unroll
      for (int nt = 0; nt < 4; ++nt) {
        int col = w * 64 + nt * 16 + lr;
        float bv = bias[col];
#pragma unroll
        for (int r = 0; r < 4; ++r) {
          int row = mt * 16 + lg * 4 + r;
          float v = eacc[mt][nt][r] + bv;
          A2[row][col] = f2bf(v);
          if (ctile == 0) out[1 + (size_t)(i0 + row) * ENT + col] = v;
        }
      }
    }
  }
  __syncthreads();

  // ---- phase 3: logits tile via MFMA ----
  f32x4 acc[2][8];
#pragma unroll
  for (int mt = 0; mt < 2; ++mt)
#pragma unroll
    for (int nt = 0; nt < 8; ++nt) acc[mt][nt] = (f32x4)(0.f);

  for (int ks = 0; ks < 8; ++ks) {
    bfx8 a0 = *reinterpret_cast<const bfx8*>(&A2[lr][ks * 32 + lg * 8]);
    bfx8 a1 = *reinterpret_cast<const bfx8*>(&A2[16 + lr][ks * 32 + lg * 8]);
#pragma unroll
    for (int nt = 0; nt < 8; ++nt) {
      int col = c0 + (w * 8 + nt) * 16 + lr;
      bfx8 bf = *reinterpret_cast<const bfx8*>(
          &LEb[(size_t)col * ENT + ks * 32 + lg * 8]);
      acc[0][nt] = __builtin_amdgcn_mfma_f32_16x16x32_bf16(a0, bf, acc[0][nt], 0, 0, 0);
      acc[1][nt] = __builtin_amdgcn_mfma_f32_16x16x32_bf16(a1, bf, acc[1][nt], 0, 0, 0);
    }
  }

  // ---- phase 4: softmax partials ----
#pragma unroll
  for (int mt = 0; mt < 2; ++mt) {
    float mrow[4], srow[4];
#pragma unroll
    for (int r = 0; r < 4; ++r) {
      float m = acc[mt][0][r];
#pragma unroll
      for (int nt = 1; nt < 8; ++nt) m = fmaxf(m, acc[mt][nt][r]);
      m = fmaxf(m, __shfl_xor(m, 1));
      m = fmaxf(m, __shfl_xor(m, 2));
      m = fmaxf(m, __shfl_xor(m, 4));
      m = fmaxf(m, __shfl_xor(m, 8));
      mrow[r] = m;
      float s = 0.f;
#pragma unroll
      for (int nt = 0; nt < 8; ++nt) s += expf(acc[mt][nt][r] - m);
      s += __shfl_xor(s, 1);
      s += __shfl_xor(s, 2);
      s += __shfl_xor(s, 4);
      s += __shfl_xor(s, 8);
      srow[r] = s;
    }
    if (lr == 0) {
#pragma unroll
      for (int r = 0; r < 4; ++r) {
        redm[w][mt * 16 + lg * 4 + r] = mrow[r];
        reds[w][mt * 16 + lg * 4 + r] = srow[r];
      }
    }
    // diag: static acc indices (rule #20)
#pragma unroll
    for (int nt = 0; nt < 8; ++nt) {
#pragma unroll
      for (int r = 0; r < 4; ++r) {
        int grow = i0 + mt * 16 + lg * 4 + r;
        int gcol = c0 + (w * 8 + nt) * 16 + lr;
        if (gcol == grow) Pdiag[grow] = acc[mt][nt][r];
      }
    }
  }
  __syncthreads();
  if (t < 32) {
    int i = i0 + t;
    float M = redm[0][t];
    M = fmaxf(M, redm[1][t]); M = fmaxf(M, redm[2][t]); M = fmaxf(M, redm[3][t]);
    float S = reds[0][t] * expf(redm[0][t] - M) + reds[1][t] * expf(redm[1][t] - M) +
              reds[2][t] * expf(redm[2][t] - M) + reds[3][t] * expf(redm[3][t] - M);
    Pmax[(i << 2) | ctile] = M;
    Psum[(i << 2) | ctile] = S;
  }
}

// ---------------------------------------------------------------------------
// K4: finalize — exact LSE combine + masked mean (1 block, 1024 thr).
// ---------------------------------------------------------------------------
__global__ __launch_bounds__(1024) void finalize_kernel(
    const float* __restrict__ Pmax, const float* __restrict__ Psum,
    const float* __restrict__ Pdiag, const int* __restrict__ labels,
    float* __restrict__ out) {
  int t = threadIdx.x;
  float ls = 0.f, cnt = 0.f;
  for (int i = t; i < NTOT; i += 1024) {
    float4 mx = reinterpret_cast<const float4*>(Pmax)[i];
    float4 sm = reinterpret_cast<const float4*>(Psum)[i];
    float M = fmaxf(fmaxf(mx.x, mx.y), fmaxf(mx.z, mx.w));
    float S = sm.x * expf(mx.x - M) + sm.y * expf(mx.y - M) +
              sm.z * expf(mx.z - M) + sm.w * expf(mx.w - M);
    float pr = (logf(S) + M) - Pdiag[i];
    int status = labels[(i >> 7) * 256 + 128 + (i & 127)];
    if (status >= 0) { ls += pr; cnt += 1.f; }
  }
  __shared__ float rs[1024], rc[1024];
  rs[t] = ls; rc[t] = cnt;
  __syncthreads();
  for (int o = 512; o > 0; o >>= 1) {
    if (t < o) { rs[t] += rs[t + o]; rc[t] += rc[t + o]; }
    __syncthreads();
  }
  if (t == 0) {
    float L = rc[0] > 0.f ? rs[0] / rc[0] : 0.f;
    if (isnan(L)) L = 0.f;
    if (isinf(L)) L = L > 0.f ? FLT_MAX : -FLT_MAX;
    out[0] = L;
  }
}

// ---------------------------------------------------------------------------
extern "C" void kernel_launch(void* const* d_in, const int* in_sizes, int n_in,
                              void* d_out, int out_size, void* d_ws,
                              size_t ws_size, hipStream_t stream) {
  const float* seq   = (const float*)d_in[0];
  const float* lw    = (const float*)d_in[1];
  const float* lb    = (const float*)d_in[2];
  const float* table = (const float*)d_in[3];
  const int* spans   = (const int*)d_in[4];
  const int* labels  = (const int*)d_in[5];
  float* out = (float*)d_out;
  float* ws = (float*)d_ws;

  // workspace layout
  float* W  = ws;                                  // [16][256][768] f32
  float* P  = W + (size_t)BSZ * NSPAN * HID;       // [16][64][768]  f32
  float* Pmax = P + (size_t)BSZ * NCH * HID;       // [2048][4]
  float* Psum = Pmax + NTOT * 4;                   // [2048][4]
  float* Pdiag = Psum + NTOT * 4;                  // [2048]
  unsigned short* LWb = (unsigned short*)(Pdiag + NTOT);  // [256][768] bf16
  unsigned short* LEb = LWb + (size_t)ENT * HID;          // [2048][256] bf16

  k1_scan_prep_kernel<<<BSZ * NCH + 128, 192, 0, stream>>>(
      seq, spans, W, P, lw, LWb, table, labels, LEb);
  chunk_prefix_kernel<<<BSZ, 192, 0, stream>>>(P);
  fused_ev_loss_kernel<<<256, 256, 0, stream>>>(
      W, P, spans, LWb, lb, LEb, Pmax, Psum, Pdiag, out);
  finalize_kernel<<<1, 1024, 0, stream>>>(Pmax, Psum, Pdiag, labels, out);
}

// Round 14
// 81.891 us; speedup vs baseline: 1.1640x; 1.1640x over previous
//
#include <hip/hip_runtime.h>
#include <hip/hip_bf16.h>
#include <math.h>
#include <float.h>

// Problem constants
#define BSZ 16
#define SEQ 4096
#define HID 768
#define H4  192      // HID/4
#define NM  128
#define NSPAN 256
#define ENT 256
#define NTOT 2048
#define SC  64
#define NCH 64

typedef __attribute__((ext_vector_type(8))) short bfx8;
typedef __attribute__((ext_vector_type(4))) float f32x4;

static __device__ __forceinline__ unsigned short f2bf(float x) {
  unsigned int u = __float_as_uint(x);
  unsigned int r = (u + 0x7fff + ((u >> 16) & 1)) >> 16;  // RNE
  return (unsigned short)r;
}

static __device__ __forceinline__ bfx8 pack8(float4 v0, float4 v1) {
  bfx8 p;
  p[0] = (short)f2bf(v0.x); p[1] = (short)f2bf(v0.y);
  p[2] = (short)f2bf(v0.z); p[3] = (short)f2bf(v0.w);
  p[4] = (short)f2bf(v1.x); p[5] = (short)f2bf(v1.y);
  p[6] = (short)f2bf(v1.z); p[7] = (short)f2bf(v1.w);
  return p;
}

// ---------------------------------------------------------------------------
// K1: scan + prep fused as independent block roles. NO device fences.
//  blocks 0..1023   : chunked scan (b=bid>>6, c=bid&63) -> W, P(chunk sums)
//  blocks 1024..1151: prep — vectorized LWb convert + LEb label-emb gather
// ---------------------------------------------------------------------------
__global__ __launch_bounds__(192) void k1_scan_prep_kernel(
    const float* __restrict__ seq, const int* __restrict__ spans,
    float* __restrict__ W, float* __restrict__ P,
    const float* __restrict__ lw, unsigned short* __restrict__ LWb,
    const float* __restrict__ table, const int* __restrict__ labels,
    unsigned short* __restrict__ LEb) {
  int bid = blockIdx.x, t = threadIdx.x;

  if (bid >= BSZ * NCH) {
    // ---- prep role (8-wide vectorized, G13) ----
    int tid = (bid - BSZ * NCH) * 192 + t;  // 0..24575
    {  // LWb: 196608 elems = 24576 chunks of 8 — exactly one per thread
      const float4* s = reinterpret_cast<const float4*>(lw) + (size_t)tid * 2;
      float4 v0 = s[0], v1 = s[1];
      *reinterpret_cast<bfx8*>(LWb + (size_t)tid * 8) = pack8(v0, v1);
    }
    for (int i8 = tid; i8 < NTOT * 32; i8 += 24576) {  // LEb: 65536 chunks
      int j = i8 >> 5, e8 = i8 & 31;
      int lab = labels[(j >> 7) * 256 + (j & 127)];  // labels[b][0][m]
      const float4* s =
          reinterpret_cast<const float4*>(table + (size_t)lab * ENT) + e8 * 2;
      float4 v0 = s[0], v1 = s[1];
      *reinterpret_cast<bfx8*>(LEb + (size_t)j * ENT + e8 * 8) = pack8(v0, v1);
    }
    return;
  }

  // ---- span-scan role ----
  int b = bid >> 6;
  int c = bid & 63;

  __shared__ int head[SC + 1];
  __shared__ int nxt[NSPAN];
  __shared__ unsigned int maskw[2];
  __shared__ int has_end;
  for (int i = t; i < SC + 1; i += 192) head[i] = -1;
  if (t < 2) maskw[t] = 0u;
  if (t == 0) has_end = 0;
  __syncthreads();
  for (int j = t; j < NSPAN; j += 192) {
    int e = spans[b * NSPAN + j];
    int ch = e >> 6; if (ch > NCH - 1) ch = NCH - 1;
    if (ch == c) {
      int off = e - c * SC;
      nxt[j] = atomicExch(&head[off], j);
      if (off < SC) atomicOr(&maskw[off >> 5], 1u << (off & 31));
      else has_end = 1;
    }
  }
  __syncthreads();
  unsigned long long mask = ((unsigned long long)maskw[1] << 32) | maskw[0];
  int emit_end = has_end;

  const float4* seq4 =
      reinterpret_cast<const float4*>(seq) + (size_t)(b * SEQ + c * SC) * H4 + t;
  float4* W4 = reinterpret_cast<float4*>(W);
  float4 acc = make_float4(0.f, 0.f, 0.f, 0.f);
#pragma unroll 8
  for (int s = 0; s < SC; ++s) {
    if (mask & (1ull << s)) {
      for (int p = head[s]; p != -1; p = nxt[p]) {
        W4[(size_t)(b * NSPAN + p) * H4 + t] = acc;
      }
    }
    float4 v = seq4[(size_t)s * H4];
    acc.x += v.x; acc.y += v.y; acc.z += v.z; acc.w += v.w;
  }
  if (emit_end) {
    for (int p = head[SC]; p != -1; p = nxt[p]) {
      W4[(size_t)(b * NSPAN + p) * H4 + t] = acc;
    }
  }
  reinterpret_cast<float4*>(P)[(size_t)(b * NCH + c) * H4 + t] = acc;
}

// ---------------------------------------------------------------------------
// K2: exclusive prefix over chunk sums (batched loads, 16 blocks).
// ---------------------------------------------------------------------------
__global__ __launch_bounds__(192) void chunk_prefix_kernel(float* __restrict__ P) {
  int b = blockIdx.x;
  int h = threadIdx.x;
  float4* P4 = reinterpret_cast<float4*>(P) + (size_t)b * NCH * H4 + h;
  float4 run = make_float4(0.f, 0.f, 0.f, 0.f);
  for (int cb = 0; cb < NCH; cb += 16) {
    float4 v[16];
#pragma unroll
    for (int i = 0; i < 16; ++i) v[i] = P4[(size_t)(cb + i) * H4];
#pragma unroll
    for (int i = 0; i < 16; ++i) {
      P4[(size_t)(cb + i) * H4] = run;
      run.x += v[i].x; run.y += v[i].y; run.z += v[i].z; run.w += v[i].w;
    }
  }
}

// ---------------------------------------------------------------------------
// K3: ev_mfma — EV[2048][256] = MV x LWb^T via 16x16x32 bf16 MFMA.
// ---------------------------------------------------------------------------
#define APAD 776
__global__ __launch_bounds__(256) void ev_mfma_kernel(
    const float* __restrict__ W, const float* __restrict__ P,
    const int* __restrict__ spans, const unsigned short* __restrict__ LWb,
    const float* __restrict__ bias, unsigned short* __restrict__ EVb,
    float* __restrict__ out) {
  int t = threadIdx.x;
  int chalf = blockIdx.x & 1;
  int i0 = (blockIdx.x >> 1) * 16;

  __shared__ unsigned short Ab[16][APAD];

  const float4* W4 = reinterpret_cast<const float4*>(W);
  const float4* P4 = reinterpret_cast<const float4*>(P);
  for (int it = 0; it < 12; ++it) {
    int q = it * 256 + t;
    int r = q / H4, h = q - r * H4;
    int bm = i0 + r;
    int b = bm >> 7, m = bm & (NM - 1);
    int e0 = spans[bm * 2], e1 = spans[bm * 2 + 1];
    int c0 = e0 >> 6; if (c0 > NCH - 1) c0 = NCH - 1;
    int c1 = e1 >> 6; if (c1 > NCH - 1) c1 = NCH - 1;
    float4 p0 = P4[(size_t)(b * NCH + c0) * H4 + h];
    float4 p1 = P4[(size_t)(b * NCH + c1) * H4 + h];
    float4 w0 = W4[(size_t)(b * NSPAN + 2 * m) * H4 + h];
    float4 w1 = W4[(size_t)(b * NSPAN + 2 * m + 1) * H4 + h];
    int len = e1 - e0;
    float inv = len > 0 ? 1.f / (float)len : 0.f;
    ushort4 pk;
    pk.x = f2bf(((p1.x + w1.x) - (p0.x + w0.x)) * inv);
    pk.y = f2bf(((p1.y + w1.y) - (p0.y + w0.y)) * inv);
    pk.z = f2bf(((p1.z + w1.z) - (p0.z + w0.z)) * inv);
    pk.w = f2bf(((p1.w + w1.w) - (p0.w + w0.w)) * inv);
    *reinterpret_cast<ushort4*>(&Ab[r][h * 4]) = pk;
  }
  __syncthreads();

  int w = t >> 6, l = t & 63;
  int lr = l & 15, lg = l >> 4;

  f32x4 acc[2];
  acc[0] = (f32x4)(0.f); acc[1] = (f32x4)(0.f);

  for (int ks = 0; ks < 24; ++ks) {
    bfx8 a = *reinterpret_cast<const bfx8*>(&Ab[lr][ks * 32 + lg * 8]);
#pragma unroll
    for (int nt = 0; nt < 2; ++nt) {
      int col = chalf * 128 + w * 32 + nt * 16 + lr;
      bfx8 bf = *reinterpret_cast<const bfx8*>(
          &LWb[(size_t)col * HID + ks * 32 + lg * 8]);
      acc[nt] = __builtin_amdgcn_mfma_f32_16x16x32_bf16(a, bf, acc[nt], 0, 0, 0);
    }
  }

#pragma unroll
  for (int nt = 0; nt < 2; ++nt) {
    int col = chalf * 128 + w * 32 + nt * 16 + lr;
    float bv = bias[col];
#pragma unroll
    for (int r = 0; r < 4; ++r) {
      int row = i0 + lg * 4 + r;
      float v = acc[nt][r] + bv;
      out[1 + (size_t)row * ENT + col] = v;
      EVb[(size_t)row * ENT + col] = f2bf(v);
    }
  }
}

// ---------------------------------------------------------------------------
// K4: loss_mfma — 32-row tiles (halves LEb L2 re-reads vs 16-row).
// Grid 256 x 256: rtile=bid>>2 (32 rows), ctile=bid&3 (512 cols).
// ---------------------------------------------------------------------------
__global__ __launch_bounds__(256) void loss_mfma_kernel(
    const unsigned short* __restrict__ EVb, const unsigned short* __restrict__ LEb,
    float* __restrict__ Pmax, float* __restrict__ Psum,
    float* __restrict__ Pdiag) {
  int t = threadIdx.x;
  int bid = blockIdx.x;
  int ctile = bid & 3, rtile = bid >> 2;
  int i0 = rtile * 32, c0 = ctile * 512;

  __shared__ unsigned short Ab[32][264];
  __shared__ float redm[4][32], reds[4][32];

  for (int q = t; q < 1024; q += 256) {    // 32 rows x 32 short8 chunks
    int r = q >> 5, c8 = q & 31;
    *reinterpret_cast<bfx8*>(&Ab[r][c8 * 8]) =
        *reinterpret_cast<const bfx8*>(&EVb[(size_t)(i0 + r) * ENT + c8 * 8]);
  }
  __syncthreads();

  int w = t >> 6, l = t & 63;
  int lr = l & 15, lg = l >> 4;

  f32x4 acc[2][8];
#pragma unroll
  for (int mt = 0; mt < 2; ++mt)
#pragma unroll
    for (int nt = 0; nt < 8; ++nt) acc[mt][nt] = (f32x4)(0.f);

  for (int ks = 0; ks < 8; ++ks) {
    bfx8 a0 = *reinterpret_cast<const bfx8*>(&Ab[lr][ks * 32 + lg * 8]);
    bfx8 a1 = *reinterpret_cast<const bfx8*>(&Ab[16 + lr][ks * 32 + lg * 8]);
#pragma unroll
    for (int nt = 0; nt < 8; ++nt) {
      int col = c0 + (w * 8 + nt) * 16 + lr;
      bfx8 bf = *reinterpret_cast<const bfx8*>(
          &LEb[(size_t)col * ENT + ks * 32 + lg * 8]);
      acc[0][nt] = __builtin_amdgcn_mfma_f32_16x16x32_bf16(a0, bf, acc[0][nt], 0, 0, 0);
      acc[1][nt] = __builtin_amdgcn_mfma_f32_16x16x32_bf16(a1, bf, acc[1][nt], 0, 0, 0);
    }
  }

#pragma unroll
  for (int mt = 0; mt < 2; ++mt) {
    float mrow[4], srow[4];
#pragma unroll
    for (int r = 0; r < 4; ++r) {
      float m = acc[mt][0][r];
#pragma unroll
      for (int nt = 1; nt < 8; ++nt) m = fmaxf(m, acc[mt][nt][r]);
      m = fmaxf(m, __shfl_xor(m, 1));
      m = fmaxf(m, __shfl_xor(m, 2));
      m = fmaxf(m, __shfl_xor(m, 4));
      m = fmaxf(m, __shfl_xor(m, 8));
      mrow[r] = m;
      float s = 0.f;
#pragma unroll
      for (int nt = 0; nt < 8; ++nt) s += expf(acc[mt][nt][r] - m);
      s += __shfl_xor(s, 1);
      s += __shfl_xor(s, 2);
      s += __shfl_xor(s, 4);
      s += __shfl_xor(s, 8);
      srow[r] = s;
    }
    if (lr == 0) {
#pragma unroll
      for (int r = 0; r < 4; ++r) {
        redm[w][mt * 16 + lg * 4 + r] = mrow[r];
        reds[w][mt * 16 + lg * 4 + r] = srow[r];
      }
    }
    // diag: static acc indices (rule #20)
#pragma unroll
    for (int nt = 0; nt < 8; ++nt) {
#pragma unroll
      for (int r = 0; r < 4; ++r) {
        int grow = i0 + mt * 16 + lg * 4 + r;
        int gcol = c0 + (w * 8 + nt) * 16 + lr;
        if (gcol == grow) Pdiag[grow] = acc[mt][nt][r];
      }
    }
  }
  __syncthreads();
  if (t < 32) {
    int i = i0 + t;
    float M = redm[0][t];
    M = fmaxf(M, redm[1][t]); M = fmaxf(M, redm[2][t]); M = fmaxf(M, redm[3][t]);
    float S = reds[0][t] * expf(redm[0][t] - M) + reds[1][t] * expf(redm[1][t] - M) +
              reds[2][t] * expf(redm[2][t] - M) + reds[3][t] * expf(redm[3][t] - M);
    Pmax[(i << 2) | ctile] = M;
    Psum[(i << 2) | ctile] = S;
  }
}

// ---------------------------------------------------------------------------
// K5: finalize — exact LSE combine + masked mean (1 block, 1024 thr).
// ---------------------------------------------------------------------------
__global__ __launch_bounds__(1024) void finalize_kernel(
    const float* __restrict__ Pmax, const float* __restrict__ Psum,
    const float* __restrict__ Pdiag, const int* __restrict__ labels,
    float* __restrict__ out) {
  int t = threadIdx.x;
  float ls = 0.f, cnt = 0.f;
  for (int i = t; i < NTOT; i += 1024) {
    float4 mx = reinterpret_cast<const float4*>(Pmax)[i];
    float4 sm = reinterpret_cast<const float4*>(Psum)[i];
    float M = fmaxf(fmaxf(mx.x, mx.y), fmaxf(mx.z, mx.w));
    float S = sm.x * expf(mx.x - M) + sm.y * expf(mx.y - M) +
              sm.z * expf(mx.z - M) + sm.w * expf(mx.w - M);
    float pr = (logf(S) + M) - Pdiag[i];
    int status = labels[(i >> 7) * 256 + 128 + (i & 127)];
    if (status >= 0) { ls += pr; cnt += 1.f; }
  }
  __shared__ float rs[1024], rc[1024];
  rs[t] = ls; rc[t] = cnt;
  __syncthreads();
  for (int o = 512; o > 0; o >>= 1) {
    if (t < o) { rs[t] += rs[t + o]; rc[t] += rc[t + o]; }
    __syncthreads();
  }
  if (t == 0) {
    float L = rc[0] > 0.f ? rs[0] / rc[0] : 0.f;
    if (isnan(L)) L = 0.f;
    if (isinf(L)) L = L > 0.f ? FLT_MAX : -FLT_MAX;
    out[0] = L;
  }
}

// ---------------------------------------------------------------------------
extern "C" void kernel_launch(void* const* d_in, const int* in_sizes, int n_in,
                              void* d_out, int out_size, void* d_ws,
                              size_t ws_size, hipStream_t stream) {
  const float* seq   = (const float*)d_in[0];
  const float* lw    = (const float*)d_in[1];
  const float* lb    = (const float*)d_in[2];
  const float* table = (const float*)d_in[3];
  const int* spans   = (const int*)d_in[4];
  const int* labels  = (const int*)d_in[5];
  float* out = (float*)d_out;
  float* ws = (float*)d_ws;

  // workspace layout
  float* W  = ws;                                  // [16][256][768] f32
  float* P  = W + (size_t)BSZ * NSPAN * HID;       // [16][64][768]  f32
  float* Pmax = P + (size_t)BSZ * NCH * HID;       // [2048][4]
  float* Psum = Pmax + NTOT * 4;                   // [2048][4]
  float* Pdiag = Psum + NTOT * 4;                  // [2048]
  unsigned short* LWb = (unsigned short*)(Pdiag + NTOT);  // [256][768] bf16
  unsigned short* LEb = LWb + (size_t)ENT * HID;          // [2048][256] bf16
  unsigned short* EVb = LEb + (size_t)NTOT * ENT;         // [2048][256] bf16

  k1_scan_prep_kernel<<<BSZ * NCH + 128, 192, 0, stream>>>(
      seq, spans, W, P, lw, LWb, table, labels, LEb);
  chunk_prefix_kernel<<<BSZ, 192, 0, stream>>>(P);
  ev_mfma_kernel<<<256, 256, 0, stream>>>(W, P, spans, LWb, lb, EVb, out);
  loss_mfma_kernel<<<256, 256, 0, stream>>>(EVb, LEb, Pmax, Psum, Pdiag);
  finalize_kernel<<<1, 1024, 0, stream>>>(Pmax, Psum, Pdiag, labels, out);
}